// Round 10
// baseline (177.484 us; speedup 1.0000x reference)
//
#include <hip/hip_runtime.h>

#define IN_F 4096
#define OUT_F 16384
#define M_ROWS 512

#define BM 128
#define BN 128
#define BK 64
#define NKT (IN_F / BK)    // 64
#define THREADS 256

typedef __bf16 bf16x8_t __attribute__((ext_vector_type(8)));
typedef float f32x4_t __attribute__((ext_vector_type(4)));
typedef int i32x4_t __attribute__((ext_vector_type(4)));

__device__ __forceinline__ void gld16(const void* g, void* l) {
    __builtin_amdgcn_global_load_lds(
        (const __attribute__((address_space(1))) void*)g,
        (__attribute__((address_space(3))) void*)l,
        16 /*bytes, literal*/, 0, 0);
}

// ---------------- pre-pass: x fp32 -> bf16, swizzled LDS tile image (r9, validated) ----------------
// xp = [4 mt][64 kt] tiles of 128r x 64c bf16 (16 KB each): linear slot (r, ch) holds
// x[mt*128+r][kt*64 + ((ch ^ (r&7))<<3) + j]; GEMM reads slot (k>>3)^(r&7).
__global__ __launch_bounds__(256)
void xpack_kernel(const float* __restrict__ x, __bf16* __restrict__ xp) {
    const int tid = blockIdx.x * 256 + (int)threadIdx.x;   // 262144 threads, 1 chunk each
    const int tile = tid >> 10;            // 1024 chunks per tile; tile = mt*64+kt
    const int r = (tid >> 3) & 127;
    const int ch = tid & 7;
    const int mt = tile >> 6;
    const int kt = tile & 63;
    const int gcol = kt * 64 + ((ch ^ (r & 7)) << 3);
    const float* src = x + (size_t)(mt * 128 + r) * IN_F + gcol;
    f32x4_t a = *(const f32x4_t*)(src);
    f32x4_t b = *(const f32x4_t*)(src + 4);
    bf16x8_t o;
    o[0] = (__bf16)a[0]; o[1] = (__bf16)a[1]; o[2] = (__bf16)a[2]; o[3] = (__bf16)a[3];
    o[4] = (__bf16)b[0]; o[5] = (__bf16)b[1]; o[6] = (__bf16)b[2]; o[7] = (__bf16)b[3];
    *(bf16x8_t*)(xp + (size_t)tid * 8) = o;
}

// ---------------- main GEMM: A LDS-dbuf via gld16, B global->reg direct ----------------
// grid 512 = 4 mt x 128 nt, 2 blocks/CU. 4 waves 1x4: wave-tile 128x32 (B disjoint
// across waves -> exact 32 KB B bytes/block/kt). LDS 32 KB (A dbuf only).
// Per kt: barrier -> issue A-DMA(kt+1)+B-regload(kt+1) -> cvt B(kt) -> MFMA(kt).
__global__ __launch_bounds__(THREADS, 2)
void qgemm10_kernel(const __bf16* __restrict__ xp, const int* __restrict__ Wq,
                    const float* __restrict__ scales, const float* __restrict__ bias,
                    float* __restrict__ out) {
    __shared__ __align__(16) unsigned char sA[2][BM * BK * 2];   // 2 x 16 KB, swizzled image

    const int bid = (int)blockIdx.x;
    const int s = bid >> 3;                      // 0..63 within XCD
    const int nt = (bid & 7) * 16 + (s >> 2);    // 0..127
    const int mt = s & 3;                        // mt-quad concurrent on one XCD (Wq L2 dedup)
    const int brow = mt * BM;
    const int bcol = nt * BN;

    const int t = (int)threadIdx.x;
    const int lane = t & 63;
    const int wid = t >> 6;        // 4 waves; wave cols [wid*32, wid*32+32)

    const int la = lane & 15;
    const int g = lane >> 4;       // k-octet index
    const int sw = lane & 7;

    // ---- A DMA: 16 KB/kt = 4 sweeps; xp is the LDS byte image ----
    const __bf16* xt = xp + (size_t)(mt * NKT) * (BM * BK) + t * 8;
    const int ldsA0 = wid * 1024;  // wave-uniform; HW adds lane*16; +i*4096 per sweep

    // ---- B direct loads: lane -> Wq row (bcol + wid*32 + n*16 + la), k = kt*64+ks*32+g*8 ----
    const int* wb = Wq + (size_t)(bcol + wid * 32 + la) * IN_F + g * 8;

    f32x4_t acc[8][2];
#pragma unroll
    for (int m = 0; m < 8; ++m)
#pragma unroll
        for (int n = 0; n < 2; ++n) {
            f32x4_t z = {0.f, 0.f, 0.f, 0.f};
            acc[m][n] = z;
        }

    i32x4_t bva[8], bvb[8];   // [n*4 + ks*2 + h]

#define ISSUE_A(KT_, PB_)                                               \
    do {                                                                \
        const __bf16* sa_ = xt + (size_t)(KT_) * (BM * BK);             \
        _Pragma("unroll") for (int i_ = 0; i_ < 4; ++i_)                \
            gld16(sa_ + i_ * 2048, &sA[PB_][0] + ldsA0 + i_ * 4096);    \
    } while (0)

#define LOAD_B(KT_, BV)                                                 \
    do {                                                                \
        _Pragma("unroll") for (int n_ = 0; n_ < 2; ++n_) {              \
            const int* p_ = wb + (size_t)n_ * 16 * IN_F + (size_t)(KT_) * BK; \
            _Pragma("unroll") for (int ks_ = 0; ks_ < 2; ++ks_) {       \
                BV[n_ * 4 + ks_ * 2 + 0] = *(const i32x4_t*)(p_ + ks_ * 32);     \
                BV[n_ * 4 + ks_ * 2 + 1] = *(const i32x4_t*)(p_ + ks_ * 32 + 4); \
            }                                                           \
        }                                                               \
    } while (0)

// One step: sync (A(KT) resident, buf^1 readers done) -> prefetch KT+1 -> cvt+MFMA KT.
#define STEP(CUR, KT, BVC, BVN)                                         \
    do {                                                                \
        __syncthreads();                                                \
        {                                                               \
            const int kn_ = ((KT) + 1 < NKT) ? (KT) + 1 : NKT - 1;      \
            ISSUE_A(kn_, (CUR) ^ 1);                                    \
            LOAD_B(kn_, BVN);                                           \
        }                                                               \
        bf16x8_t bf_[2][2];                                             \
        _Pragma("unroll") for (int n_ = 0; n_ < 2; ++n_)                \
            _Pragma("unroll") for (int ks_ = 0; ks_ < 2; ++ks_) {       \
                i32x4_t lo_ = BVC[n_ * 4 + ks_ * 2 + 0];                \
                i32x4_t hi_ = BVC[n_ * 4 + ks_ * 2 + 1];                \
                _Pragma("unroll") for (int j_ = 0; j_ < 4; ++j_) {      \
                    bf_[n_][ks_][j_] = (__bf16)(float)lo_[j_];          \
                    bf_[n_][ks_][4 + j_] = (__bf16)(float)hi_[j_];      \
                }                                                       \
            }                                                           \
        _Pragma("unroll") for (int ks_ = 0; ks_ < 2; ++ks_) {           \
            bf16x8_t af_[8];                                            \
            _Pragma("unroll") for (int m_ = 0; m_ < 8; ++m_) {          \
                const int r_ = la + m_ * 16;                            \
                af_[m_] = *(const bf16x8_t*)(&sA[CUR][0] + r_ * 128 +   \
                                             (((ks_ * 4 + g) ^ sw) << 4)); \
            }                                                           \
            __builtin_amdgcn_s_setprio(1);                              \
            _Pragma("unroll") for (int m_ = 0; m_ < 8; ++m_)            \
                _Pragma("unroll") for (int n_ = 0; n_ < 2; ++n_)        \
                    acc[m_][n_] = __builtin_amdgcn_mfma_f32_16x16x32_bf16( \
                        af_[m_], bf_[n_][ks_], acc[m_][n_], 0, 0, 0);   \
            __builtin_amdgcn_s_setprio(0);                              \
        }                                                               \
    } while (0)

    // -------- prologue: tile 0 in flight --------
    ISSUE_A(0, 0);
    LOAD_B(0, bva);

#pragma unroll 1
    for (int kt = 0; kt < NKT; kt += 2) {
        STEP(0, kt, bva, bvb);
        STEP(1, kt + 1, bvb, bva);
    }
#undef ISSUE_A
#undef LOAD_B
#undef STEP

    // ---- epilogue: per-col dequant scale + bias, direct fp32 store ----
    // C/D layout: col = lane&15, row = (lane>>4)*4 + reg (m89-verified, r1-r9-validated)
    const int orow0 = brow + (g << 2);
    const int ocol0 = bcol + wid * 32 + la;
#pragma unroll
    for (int n = 0; n < 2; ++n) {
        const int c = ocol0 + n * 16;
        const float sc = scales[c];
        const float bs = bias[c];
#pragma unroll
        for (int m = 0; m < 8; ++m) {
            const int r = orow0 + m * 16;
            float* po = out + (size_t)r * OUT_F + c;
#pragma unroll
            for (int j = 0; j < 4; ++j) {
                po[(size_t)j * OUT_F] = acc[m][n][j] * sc + bs;
            }
        }
    }
}

// ---------------- fallback (no workspace): round-1 kernel, known-correct ----------------
__global__ __launch_bounds__(256, 2)
void qgemm_fallback(const float* __restrict__ x, const int* __restrict__ Wq,
                    const float* __restrict__ scales, const float* __restrict__ bias,
                    float* __restrict__ out) {
    __shared__ __align__(16) unsigned char fA[128 * 64 * 2];
    __shared__ __align__(16) unsigned char fB[128 * 64 * 2];

    const int bid = (int)blockIdx.x;
    const int gsw = (bid & 7) * 64 + (bid >> 3);
    const int mt = gsw & 3;
    const int ntf = gsw >> 2;
    const int brow = mt * 128;
    const int bcolf = ntf * 128;

    const int t = (int)threadIdx.x;
    const int lane = t & 63;
    const int wid = t >> 6;
    const int wr = wid >> 1;
    const int wc = wid & 1;

    const int srow = t >> 4;
    const int sc4 = t & 15;

    const float* xg = x + (size_t)(brow + srow) * IN_F + sc4 * 4;
    const int* wgf = Wq + (size_t)(bcolf + srow) * IN_F + sc4 * 4;

    f32x4_t acc[4][4];
#pragma unroll
    for (int i = 0; i < 4; ++i)
#pragma unroll
        for (int j = 0; j < 4; ++j) {
            f32x4_t z = {0.f, 0.f, 0.f, 0.f};
            acc[i][j] = z;
        }

    const int frow_a = wr * 64 + (lane & 15);
    const int frow_b = wc * 64 + (lane & 15);
    const int fk = (lane >> 4) * 16;

#pragma unroll 1
    for (int kt = 0; kt < IN_F / 64; ++kt) {
        const int k0 = kt * 64;
        f32x4_t av[8];
        i32x4_t bvf[8];
#pragma unroll
        for (int i = 0; i < 8; ++i) {
            av[i] = *(const f32x4_t*)(xg + k0 + (size_t)i * 16 * IN_F);
            bvf[i] = *(const i32x4_t*)(wgf + k0 + (size_t)i * 16 * IN_F);
        }
        __syncthreads();
#pragma unroll
        for (int i = 0; i < 8; ++i) {
            const int row = srow + i * 16;
            unsigned off = (unsigned)(row * 128 + sc4 * 8);
            off ^= (unsigned)(row & 7) << 4;
            __bf16 pa[4], pb[4];
#pragma unroll
            for (int j = 0; j < 4; ++j) {
                pa[j] = (__bf16)av[i][j];
                pb[j] = (__bf16)(float)bvf[i][j];
            }
            *(unsigned long long*)(fA + off) = *(unsigned long long*)pa;
            *(unsigned long long*)(fB + off) = *(unsigned long long*)pb;
        }
        __syncthreads();
#pragma unroll
        for (int ks = 0; ks < 2; ++ks) {
            bf16x8_t afv[4], bfv[4];
#pragma unroll
            for (int m = 0; m < 4; ++m) {
                const int row = frow_a + m * 16;
                afv[m] = *(const bf16x8_t*)(fA + (row * 128 + ((ks * 64 + fk) ^ ((row & 7) << 4))));
            }
#pragma unroll
            for (int n = 0; n < 4; ++n) {
                const int row = frow_b + n * 16;
                bfv[n] = *(const bf16x8_t*)(fB + (row * 128 + ((ks * 64 + fk) ^ ((row & 7) << 4))));
            }
#pragma unroll
            for (int m = 0; m < 4; ++m)
#pragma unroll
                for (int n = 0; n < 4; ++n)
                    acc[m][n] = __builtin_amdgcn_mfma_f32_16x16x32_bf16(
                        afv[m], bfv[n], acc[m][n], 0, 0, 0);
        }
    }

    const int orow = brow + wr * 64 + ((lane >> 4) << 2);
    const int ocol = bcolf + wc * 64 + (lane & 15);
#pragma unroll
    for (int n = 0; n < 4; ++n) {
        const int c = ocol + n * 16;
        const float sc = scales[c];
        const float bs = bias[c];
#pragma unroll
        for (int m = 0; m < 4; ++m) {
            const int r = orow + m * 16;
            float* po = out + (size_t)r * OUT_F + c;
#pragma unroll
            for (int j = 0; j < 4; ++j) {
                po[(size_t)j * OUT_F] = acc[m][n][j] * sc + bs;
            }
        }
    }
}

extern "C" void kernel_launch(void* const* d_in, const int* in_sizes, int n_in,
                              void* d_out, int out_size, void* d_ws, size_t ws_size,
                              hipStream_t stream) {
    const float* x = (const float*)d_in[0];
    const int* Wq = (const int*)d_in[1];
    const float* scales = (const float*)d_in[2];
    const float* bias = (const float*)d_in[3];
    float* out = (float*)d_out;

    const size_t xp_bytes = (size_t)M_ROWS * IN_F * 2;  // 4 MB
    const bool pre = (ws_size >= xp_bytes) && (d_ws != nullptr);

    if (pre) {
        __bf16* xp = (__bf16*)d_ws;
        xpack_kernel<<<dim3((M_ROWS * IN_F / 8) / 256), dim3(256), 0, stream>>>(x, xp);
        qgemm10_kernel<<<dim3(512), dim3(THREADS), 0, stream>>>(xp, Wq, scales, bias, out);
    } else {
        qgemm_fallback<<<dim3(512), dim3(256), 0, stream>>>(x, Wq, scales, bias, out);
    }
}